// Round 8
// baseline (55.239 us; speedup 1.0000x reference)
//
#include <hip/hip_runtime.h>
#include <hip/hip_cooperative_groups.h>
#include <math.h>

namespace cg = cooperative_groups;

#define HIDDEN   100
#define NCLASS   4
#define NWORDS   40
#define VOCAB    50000
#define PCAP     5120
#define MAXC     24        // chain nodes of a[] staged in GRU LDS (L expected ~10)
#define MAXCHAIN 200
#define NTHR     640
#define NBLK     48

// ws layout: byte 64: float a[MAXCHAIN][3*HIDDEN]

__global__ __launch_bounds__(NTHR) void k_coop(
    const float* __restrict__ xvals, const int* __restrict__ xidx,
    const int* __restrict__ tree, const int* __restrict__ np_ptr,
    const float* __restrict__ E,
    const float* __restrict__ Wz, const float* __restrict__ bz,
    const float* __restrict__ Wr, const float* __restrict__ br,
    const float* __restrict__ Wh, const float* __restrict__ bh,
    const float* __restrict__ Uz, const float* __restrict__ Ur,
    const float* __restrict__ Uh,
    const float* __restrict__ Wout, const float* __restrict__ bout,
    float* __restrict__ a, float* __restrict__ out)
{
    __shared__ int P[PCAP];
    __shared__ int chain[MAXCHAIN];
    __shared__ int len_s;
    __shared__ __align__(16) float xe[HIDDEN + 4];
    __shared__ __align__(16) float a_lds[MAXC * 3 * HIDDEN];   // 28.8 KB (block 0)
    __shared__ __align__(16) float h0[112], h1[112], zbuf[112], rbuf[112];
    __shared__ __align__(16) float wout_s[NCLASS * HIDDEN];
    __shared__ float bout_s[NCLASS];
    __shared__ float ov[NCLASS];

    const int t    = threadIdx.x;
    const int bid  = blockIdx.x;
    const int half = t & 1;
    const int npar = np_ptr[0];
    const int pcap = (npar < PCAP) ? npar : PCAP;

    // ---- block 0: U half-row preload + W_out stage — hidden under producers ----
    float2 ureg[25];
    int grow = 0;
    if (bid == 0) {
        if (t < 600) {
            grow = (t < 400) ? (t >> 1) : (200 + ((t - 400) >> 1));
            int m = grow / HIDDEN, ri = grow - m * HIDDEN;
            const float* Um = (m == 0 ? Uz : (m == 1 ? Ur : Uh));
            const float2* u2 = (const float2*)(Um + ri * HIDDEN + half * 50);
            #pragma unroll
            for (int k = 0; k < 25; ++k) ureg[k] = u2[k];
        }
        if (t < NCLASS * HIDDEN) wout_s[t] = Wout[t];
        if (t < NCLASS) bout_s[t] = bout[t];
    }

    // ---- producers: W half-row preload (latency hides under P-stage + chase) ----
    float2 wreg[25];
    float  bias = 0.f;
    int row = 0;
    if (bid > 0 && t < 600) {
        row = t >> 1;
        int m = row / HIDDEN, ri = row - m * HIDDEN;
        const float* Wm = (m == 0 ? Wz : (m == 1 ? Wr : Wh));
        const float2* w2 = (const float2*)(Wm + ri * HIDDEN + half * 50);
        #pragma unroll
        for (int k = 0; k < 25; ++k) wreg[k] = w2[k];
        if (half == 0) bias = (m == 0 ? bz : (m == 1 ? br : bh))[ri];
    }

    // ---- all blocks: parents -> LDS (coalesced int2), chase chain of node npar-1 ----
    const int2* tree2 = (const int2*)tree;
    for (int i = t; i < pcap; i += NTHR) P[i] = tree2[i].x;
    __syncthreads();
    if (t == 0) {
        int len = 0, i = npar - 1; if (i < 0) i = 0;
        while (i > 0 && len < MAXCHAIN - 1) { chain[len++] = i; i = (i < pcap) ? P[i] : tree[2 * i]; }
        chain[len++] = i;                    // node 0 (zero parent state)
        len_s = len;
    }
    __syncthreads();
    const int L = len_s;

    // ---- producers: gather + W matvec for node d = bid-1 (+47 stride fallback) ----
    if (bid >= 1) {
        for (int d = bid - 1; d < L; d += NBLK - 1) {
            const int c = chain[d];
            if (t < 4 * HIDDEN) {            // 400 units, quad shfl reduce, 10 ILP loads
                int h = t >> 2, wg = t & 3;
                const int*   ixp = xidx  + (size_t)c * NWORDS + wg * 10;
                const float* vp  = xvals + (size_t)c * NWORDS + wg * 10;
                int ix[10]; float vv[10];
                #pragma unroll
                for (int w = 0; w < 10; ++w) ix[w] = ixp[w];
                #pragma unroll
                for (int w = 0; w < 10; ++w) vv[w] = vp[w];
                const float* Eh = E + (size_t)h * VOCAB;
                float s0 = 0.f, s1 = 0.f;
                #pragma unroll
                for (int w = 0; w < 10; ++w) {
                    float p = vv[w] * Eh[ix[w]];
                    if (w & 1) s1 += p; else s0 += p;
                }
                float p = s0 + s1;
                p += __shfl_xor(p, 1);
                p += __shfl_xor(p, 2);
                if (wg == 0) xe[h] = p;
            }
            __syncthreads();
            if (t < 600) {                   // a[d][row] = b[row] + W[row,:].xe
                const float2* x2 = (const float2*)(xe + half * 50);
                float a0 = 0.f, a1 = 0.f;
                #pragma unroll
                for (int k = 0; k < 25; ++k) {
                    float2 w = wreg[k], x = x2[k];
                    a0 += w.x * x.x; a1 += w.y * x.y;
                }
                float p = a0 + a1;
                p += __shfl_xor(p, 1);
                if (half == 0) a[d * 3 * HIDDEN + row] = p + bias;
            }
            __syncthreads();
        }
        __threadfence();                     // make a[] device-visible before the barrier
    }

    cg::this_grid().sync();
    if (bid != 0) return;

    // ================== block 0: GRU recurrence ==================
    __builtin_amdgcn_fence(__ATOMIC_ACQUIRE, "agent");   // invalidate stale cached a[]

    // batched prefetch of a[0..MAXC*300) into LDS (beyond L*300 is unread garbage)
    float ar[12];
    #pragma unroll
    for (int j = 0; j < 12; ++j) {
        int k = t + j * NTHR;
        if (k < MAXC * 3 * HIDDEN) ar[j] = a[k];
    }
    #pragma unroll
    for (int j = 0; j < 12; ++j) {
        int k = t + j * NTHR;
        if (k < MAXC * 3 * HIDDEN) a_lds[k] = ar[j];
    }
    if (t < 112) { h0[t] = 0.f; h1[t] = 0.f; }
    __syncthreads();

    float* hc = h0;
    float* hn = h1;
    for (int d = L - 1; d >= 0; --d) {
        const float* ad = (d < MAXC) ? (a_lds + d * 3 * HIDDEN) : (a + d * 3 * HIDDEN);
        if (t < 400) {                       // z and r rows (0..199)
            const float2* h2 = (const float2*)(hc + half * 50);   // 2-addr broadcast
            float a0 = 0.f, a1 = 0.f;
            #pragma unroll
            for (int k = 0; k < 25; ++k) {
                float2 u = ureg[k], x = h2[k];
                a0 += u.x * x.x; a1 += u.y * x.y;
            }
            float p = a0 + a1;
            p += __shfl_xor(p, 1);
            if (half == 0) {
                float v = fminf(fmaxf(ad[grow] + p, 0.f), 1.f);   // Hardtanh(0,1)
                if (grow < HIDDEN) zbuf[grow] = v;                           // z
                else               rbuf[grow - HIDDEN] = v * hc[grow - HIDDEN]; // r*h
            }
        }
        __syncthreads();
        if (t >= 400 && t < 600) {           // c rows (200..299) + state update
            const float2* r2 = (const float2*)(rbuf + half * 50);
            float a0 = 0.f, a1 = 0.f;
            #pragma unroll
            for (int k = 0; k < 25; ++k) {
                float2 u = ureg[k], x = r2[k];
                a0 += u.x * x.x; a1 += u.y * x.y;
            }
            float p = a0 + a1;
            p += __shfl_xor(p, 1);
            if (half == 0) {
                int i = grow - 200;
                float c = tanhf(ad[grow] + p);
                float z = zbuf[i];
                hn[i] = (1.f - z) * hc[i] + z * c;
            }
        }
        __syncthreads();
        float* tmp = hc; hc = hn; hn = tmp;
    }

    if (t < NCLASS) {
        float acc = bout_s[t];
        const float* wr = wout_s + t * HIDDEN;
        for (int j = 0; j < HIDDEN; ++j) acc += wr[j] * hc[j];
        ov[t] = acc;
    }
    __syncthreads();
    if (t == 0) {
        float mx = fmaxf(fmaxf(ov[0], ov[1]), fmaxf(ov[2], ov[3]));
        float e0 = expf(ov[0] - mx), e1 = expf(ov[1] - mx);
        float e2 = expf(ov[2] - mx), e3 = expf(ov[3] - mx);
        float s = e0 + e1 + e2 + e3;
        out[0] = e0 / s; out[1] = e1 / s; out[2] = e2 / s; out[3] = e3 / s;
    }
}

extern "C" void kernel_launch(void* const* d_in, const int* in_sizes, int n_in,
                              void* d_out, int out_size, void* d_ws, size_t ws_size,
                              hipStream_t stream) {
    const float* xvals = (const float*)d_in[0];
    const int*   xidx  = (const int*)d_in[1];
    const int*   tree  = (const int*)d_in[2];
    const int*   npar  = (const int*)d_in[3];
    const float* E     = (const float*)d_in[4];
    const float* Wz    = (const float*)d_in[5];
    const float* Uz    = (const float*)d_in[6];
    const float* bz    = (const float*)d_in[7];
    const float* Wr    = (const float*)d_in[8];
    const float* Ur    = (const float*)d_in[9];
    const float* br    = (const float*)d_in[10];
    const float* Wh    = (const float*)d_in[11];
    const float* Uh    = (const float*)d_in[12];
    const float* bh    = (const float*)d_in[13];
    const float* Wout  = (const float*)d_in[14];
    const float* bout  = (const float*)d_in[15];

    float* a   = (float*)((char*)d_ws + 64);
    float* outp = (float*)d_out;

    void* kargs[] = {
        (void*)&xvals, (void*)&xidx, (void*)&tree, (void*)&npar, (void*)&E,
        (void*)&Wz, (void*)&bz, (void*)&Wr, (void*)&br, (void*)&Wh, (void*)&bh,
        (void*)&Uz, (void*)&Ur, (void*)&Uh, (void*)&Wout, (void*)&bout,
        (void*)&a, (void*)&outp
    };
    hipLaunchCooperativeKernel((const void*)k_coop, dim3(NBLK), dim3(NTHR),
                               kargs, 0, stream);
}

// Round 9
// 27.375 us; speedup vs baseline: 2.0178x; 2.0178x over previous
//
#include <hip/hip_runtime.h>
#include <math.h>

#define HIDDEN   100
#define NCLASS   4
#define NWORDS   40
#define VOCAB    50000
#define PCAP     5120
#define MAXC     24        // chain nodes of a[] staged in GRU LDS (L expected ~10)
#define MAXCHAIN 200
#define NTHR_P   640
#define NTHR_G   1024
#define PREP_BLKS 48

// ws layout: byte 0: int len; byte 64: float a[MAXCHAIN][3*HIDDEN]

__global__ __launch_bounds__(NTHR_P) void k_prep(
    const float* __restrict__ xvals, const int* __restrict__ xidx,
    const int* __restrict__ tree, const int* __restrict__ np_ptr,
    const float* __restrict__ E,
    const float* __restrict__ Wz, const float* __restrict__ bz,
    const float* __restrict__ Wr, const float* __restrict__ br,
    const float* __restrict__ Wh, const float* __restrict__ bh,
    int* __restrict__ len_out, float* __restrict__ a)
{
    __shared__ int P[PCAP];
    __shared__ int chain[MAXCHAIN];
    __shared__ int len_s;
    __shared__ __align__(16) float xe[HIDDEN + 4];

    const int t = threadIdx.x;
    const int npar = np_ptr[0];
    const int pcap = (npar < PCAP) ? npar : PCAP;

    // W half-row preload: 25 independent float2 loads; latency hides under staging+chase
    float2 wreg[25];
    float bias = 0.f;
    int row = 0, half = t & 1;
    if (t < 600) {
        row = t >> 1;
        int m = row / HIDDEN, ri = row - m * HIDDEN;
        const float* Wm = (m == 0 ? Wz : (m == 1 ? Wr : Wh));
        const float2* w2 = (const float2*)(Wm + ri * HIDDEN + half * 50);
        #pragma unroll
        for (int k = 0; k < 25; ++k) wreg[k] = w2[k];
        if (half == 0) bias = (m == 0 ? bz : (m == 1 ? br : bh))[ri];
    }

    // parents -> LDS (coalesced int2.x), chase ancestor chain of node npar-1
    const int2* tree2 = (const int2*)tree;
    for (int i = t; i < pcap; i += NTHR_P) P[i] = tree2[i].x;
    __syncthreads();
    if (t == 0) {
        int len = 0, i = npar - 1; if (i < 0) i = 0;
        while (i > 0 && len < MAXCHAIN - 1) { chain[len++] = i; i = (i < pcap) ? P[i] : tree[2 * i]; }
        chain[len++] = i;                       // node 0 (zero parent state)
        len_s = len;
        if (blockIdx.x == 0) *len_out = len;
    }
    __syncthreads();
    const int L = len_s;

    for (int d = blockIdx.x; d < L; d += gridDim.x) {
        const int c = chain[d];
        // xe[h] = sum_w val[w] * E[h, idx[w]] : 400 units, quad shfl reduce, 10 ILP loads
        if (t < 4 * HIDDEN) {
            int h = t >> 2, wg = t & 3;
            const int*   ixp = xidx  + (size_t)c * NWORDS + wg * 10;
            const float* vp  = xvals + (size_t)c * NWORDS + wg * 10;
            int ix[10]; float vv[10];
            #pragma unroll
            for (int w = 0; w < 10; ++w) ix[w] = ixp[w];
            #pragma unroll
            for (int w = 0; w < 10; ++w) vv[w] = vp[w];
            const float* Eh = E + (size_t)h * VOCAB;
            float s0 = 0.f, s1 = 0.f;
            #pragma unroll
            for (int w = 0; w < 10; ++w) {
                float p = vv[w] * Eh[ix[w]];
                if (w & 1) s1 += p; else s0 += p;
            }
            float p = s0 + s1;
            p += __shfl_xor(p, 1);
            p += __shfl_xor(p, 2);
            if (wg == 0) xe[h] = p;
        }
        __syncthreads();
        // a[d][row] = b[row] + W[row,:] . xe : 600 half-row units
        if (t < 600) {
            const float2* x2 = (const float2*)(xe + half * 50);
            float a0 = 0.f, a1 = 0.f;
            #pragma unroll
            for (int k = 0; k < 25; ++k) {
                float2 w = wreg[k], x = x2[k];
                a0 += w.x * x.x; a1 += w.y * x.y;
            }
            float p = a0 + a1;
            p += __shfl_xor(p, 1);
            if (half == 0) a[d * 3 * HIDDEN + row] = p + bias;
        }
        __syncthreads();
    }
}

__global__ __launch_bounds__(NTHR_G) void k_gru(
    const float* __restrict__ Uz, const float* __restrict__ Ur,
    const float* __restrict__ Uh,
    const float* __restrict__ Wout, const float* __restrict__ bout,
    const int* __restrict__ len_p, const float* __restrict__ a,
    float* __restrict__ out)
{
    __shared__ __align__(16) float a_lds[MAXC * 3 * HIDDEN];   // 28.8 KB
    __shared__ __align__(16) float h0[112], h1[112], zbuf[112], rbuf[112];
    __shared__ float ov[NCLASS];

    const int t = threadIdx.x;
    const int half = t & 1;

    // two concurrent latency streams:
    //   threads 0..599   : U half-row -> registers (rows 0..199 = Uz,Ur; 200..299 = Uh)
    //   threads 600..1023: a[] -> LDS (optimistic MAXC nodes; beyond L*300 is unread)
    float2 ureg[25];
    int grow = 0;
    if (t < 600) {
        grow = (t < 400) ? (t >> 1) : (200 + ((t - 400) >> 1));
        int m = grow / HIDDEN, ri = grow - m * HIDDEN;
        const float* Um = (m == 0 ? Uz : (m == 1 ? Ur : Uh));
        const float2* u2 = (const float2*)(Um + ri * HIDDEN + half * 50);
        #pragma unroll
        for (int k = 0; k < 25; ++k) ureg[k] = u2[k];
    } else {
        const int ts = t - 600;                       // 0..423
        float ar[17];
        #pragma unroll
        for (int j = 0; j < 17; ++j) {
            int k = ts + j * 424;
            if (k < MAXC * 3 * HIDDEN) ar[j] = a[k];
        }
        #pragma unroll
        for (int j = 0; j < 17; ++j) {
            int k = ts + j * 424;
            if (k < MAXC * 3 * HIDDEN) a_lds[k] = ar[j];
        }
    }
    const int L = *len_p;
    if (t < 112) { h0[t] = 0.f; h1[t] = 0.f; }
    __syncthreads();

    // ---- first step (d = L-1, node 0): parent h = 0 -> pure pointwise ----
    {
        const float* ad = (L - 1 < MAXC) ? (a_lds + (L - 1) * 3 * HIDDEN)
                                         : (a + (L - 1) * 3 * HIDDEN);
        if (t < HIDDEN) {
            float z = fminf(fmaxf(ad[t], 0.f), 1.f);          // Hardtanh(0,1)
            h1[t] = z * tanhf(ad[2 * HIDDEN + t]);            // (1-z)*0 + z*tanh(a_h)
        }
    }
    __syncthreads();

    float* hc = h1;
    float* hn = h0;
    for (int d = L - 2; d >= 0; --d) {
        const float* ad = (d < MAXC) ? (a_lds + d * 3 * HIDDEN) : (a + d * 3 * HIDDEN);
        if (t < 400) {                           // z and r rows (0..199)
            const float2* h2 = (const float2*)(hc + half * 50);   // 2-addr broadcast
            float a0 = 0.f, a1 = 0.f;
            #pragma unroll
            for (int k = 0; k < 25; ++k) {
                float2 u = ureg[k], x = h2[k];
                a0 += u.x * x.x; a1 += u.y * x.y;
            }
            float p = a0 + a1;
            p += __shfl_xor(p, 1);
            if (half == 0) {
                float v = fminf(fmaxf(ad[grow] + p, 0.f), 1.f);   // Hardtanh(0,1)
                if (grow < HIDDEN) zbuf[grow] = v;                           // z
                else               rbuf[grow - HIDDEN] = v * hc[grow - HIDDEN]; // r*h
            }
        }
        __syncthreads();
        if (t >= 400 && t < 600) {               // c rows (200..299) + state update
            const float2* r2 = (const float2*)(rbuf + half * 50);
            float a0 = 0.f, a1 = 0.f;
            #pragma unroll
            for (int k = 0; k < 25; ++k) {
                float2 u = ureg[k], x = r2[k];
                a0 += u.x * x.x; a1 += u.y * x.y;
            }
            float p = a0 + a1;
            p += __shfl_xor(p, 1);
            if (half == 0) {
                int i = grow - 200;
                float c = tanhf(ad[grow] + p);
                float z = zbuf[i];
                hn[i] = (1.f - z) * hc[i] + z * c;
            }
        }
        __syncthreads();
        float* tmp = hc; hc = hn; hn = tmp;
    }

    if (t < NCLASS) {
        float acc = bout[t];
        const float* wr = Wout + t * HIDDEN;
        for (int j = 0; j < HIDDEN; ++j) acc += wr[j] * hc[j];
        ov[t] = acc;
    }
    __syncthreads();
    if (t == 0) {
        float mx = fmaxf(fmaxf(ov[0], ov[1]), fmaxf(ov[2], ov[3]));
        float e0 = expf(ov[0] - mx), e1 = expf(ov[1] - mx);
        float e2 = expf(ov[2] - mx), e3 = expf(ov[3] - mx);
        float s = e0 + e1 + e2 + e3;
        out[0] = e0 / s; out[1] = e1 / s; out[2] = e2 / s; out[3] = e3 / s;
    }
}

extern "C" void kernel_launch(void* const* d_in, const int* in_sizes, int n_in,
                              void* d_out, int out_size, void* d_ws, size_t ws_size,
                              hipStream_t stream) {
    const float* xvals = (const float*)d_in[0];
    const int*   xidx  = (const int*)d_in[1];
    const int*   tree  = (const int*)d_in[2];
    const int*   npar  = (const int*)d_in[3];
    const float* E     = (const float*)d_in[4];
    const float* Wz    = (const float*)d_in[5];
    const float* Uz    = (const float*)d_in[6];
    const float* bz    = (const float*)d_in[7];
    const float* Wr    = (const float*)d_in[8];
    const float* Ur    = (const float*)d_in[9];
    const float* br    = (const float*)d_in[10];
    const float* Wh    = (const float*)d_in[11];
    const float* Uh    = (const float*)d_in[12];
    const float* bh    = (const float*)d_in[13];
    const float* Wout  = (const float*)d_in[14];
    const float* bout  = (const float*)d_in[15];

    int*   len = (int*)d_ws;
    float* a   = (float*)((char*)d_ws + 64);

    k_prep<<<PREP_BLKS, NTHR_P, 0, stream>>>(xvals, xidx, tree, npar, E,
                                             Wz, bz, Wr, br, Wh, bh, len, a);
    k_gru<<<1, NTHR_G, 0, stream>>>(Uz, Ur, Uh, Wout, bout, len, a, (float*)d_out);
}

// Round 10
// 25.743 us; speedup vs baseline: 2.1457x; 1.0634x over previous
//
#include <hip/hip_runtime.h>
#include <math.h>

#define HIDDEN   100
#define NCLASS   4
#define NWORDS   40
#define VOCAB    50000
#define PCAP     5120
#define MAXC     24        // chain nodes of a[] staged in GRU LDS (L expected ~10)
#define MAXCHAIN 200
#define NTHR_P   640
#define NTHR_G   1024
#define PREP_BLKS 48
#define NODES_PER (PREP_BLKS / 4)   // 12 nodes in flight, 4 h-chunk blocks each

// ws layout: byte 0: int len; byte 64: float a4[MAXCHAIN][4][300] (per-chunk partials)

__global__ __launch_bounds__(NTHR_P) void k_prep(
    const float* __restrict__ xvals, const int* __restrict__ xidx,
    const int* __restrict__ tree, const int* __restrict__ np_ptr,
    const float* __restrict__ E,
    const float* __restrict__ Wz, const float* __restrict__ bz,
    const float* __restrict__ Wr, const float* __restrict__ br,
    const float* __restrict__ Wh, const float* __restrict__ bh,
    int* __restrict__ len_out, float* __restrict__ a4)
{
    __shared__ int P[PCAP];
    __shared__ int chain[MAXCHAIN];
    __shared__ int len_s;
    __shared__ float xe_c[32];                 // 25 used

    const int t  = threadIdx.x;
    const int q  = blockIdx.x & 3;             // h-chunk 0..3
    const int d0 = blockIdx.x >> 2;            // starting node index
    const int h0 = q * 25;
    const int npar = np_ptr[0];
    const int pcap = (npar < PCAP) ? npar : PCAP;

    // W-slice preload (issue first, hides under P-stage): row t, cols h0..h0+24
    float wsl[25];
    float bias = 0.f;
    if (t < 300) {
        int m = t / HIDDEN, i = t - m * HIDDEN;
        const float* Wm = (m == 0 ? Wz : (m == 1 ? Wr : Wh));
        const float* src = Wm + i * HIDDEN + h0;
        #pragma unroll
        for (int k = 0; k < 25; ++k) wsl[k] = src[k];
        if (q == 0) bias = (m == 0 ? bz : (m == 1 ? br : bh))[i];
    }

    // parents -> LDS (coalesced int2.x), chase ancestor chain of node npar-1
    const int2* tree2 = (const int2*)tree;
    for (int i = t; i < pcap; i += NTHR_P) P[i] = tree2[i].x;
    __syncthreads();
    if (t == 0) {
        int len = 0, i = npar - 1; if (i < 0) i = 0;
        while (i > 0 && len < MAXCHAIN - 1) { chain[len++] = i; i = (i < pcap) ? P[i] : tree[2 * i]; }
        chain[len++] = i;                      // node 0 (zero parent state)
        len_s = len;
        if (blockIdx.x == 0) *len_out = len;
    }
    __syncthreads();
    const int L = len_s;

    for (int d = d0; d < L; d += NODES_PER) {
        const int c = chain[d];
        // xe_c[hl] = sum_w val[w]*E[h0+hl, idx[w]] : 200 units (25 h x 8 wgrp), 5 loads each
        if (t < 200) {
            int hl = t >> 3, wg = t & 7;
            const int*   ixp = xidx  + (size_t)c * NWORDS + wg * 5;
            const float* vp  = xvals + (size_t)c * NWORDS + wg * 5;
            int ix[5]; float vv[5];
            #pragma unroll
            for (int w = 0; w < 5; ++w) ix[w] = ixp[w];
            #pragma unroll
            for (int w = 0; w < 5; ++w) vv[w] = vp[w];
            const float* Eh = E + (size_t)(h0 + hl) * VOCAB;
            float s0 = 0.f, s1 = 0.f;
            #pragma unroll
            for (int w = 0; w < 5; ++w) {
                float p = vv[w] * Eh[ix[w]];
                if (w & 1) s1 += p; else s0 += p;
            }
            float p = s0 + s1;
            p += __shfl_xor(p, 1);
            p += __shfl_xor(p, 2);
            p += __shfl_xor(p, 4);
            if (wg == 0) xe_c[hl] = p;
        }
        __syncthreads();
        // a4[d][q][row] = (q==0? b[row]:0) + W[row, h0:h0+25] . xe_c
        if (t < 300) {
            float a0 = 0.f, a1 = 0.f;
            #pragma unroll
            for (int k = 0; k < 25; ++k) {
                float p = wsl[k] * xe_c[k];    // xe_c broadcast read
                if (k & 1) a1 += p; else a0 += p;
            }
            a4[(d * 4 + q) * 300 + t] = a0 + a1 + bias;
        }
        __syncthreads();
    }
}

__global__ __launch_bounds__(NTHR_G) void k_gru(
    const float* __restrict__ Uz, const float* __restrict__ Ur,
    const float* __restrict__ Uh,
    const float* __restrict__ Wout, const float* __restrict__ bout,
    const int* __restrict__ len_p, const float* __restrict__ a4,
    float* __restrict__ out)
{
    __shared__ __align__(16) float a_lds[MAXC * 3 * HIDDEN];   // 28.8 KB
    __shared__ __align__(16) float h0[112], h1[112], zbuf[112], rbuf[112];
    __shared__ float ov[NCLASS];

    const int t = threadIdx.x;
    const int half = t & 1;
    const int L = *len_p;

    // two concurrent latency streams:
    //   threads 0..599   : U half-row -> registers
    //   threads 600..1023: a_lds[d*300+r] = sum of 4 chunk partials (L3-resident)
    float2 ureg[25];
    int grow = 0;
    if (t < 600) {
        grow = (t < 400) ? (t >> 1) : (200 + ((t - 400) >> 1));
        int m = grow / HIDDEN, ri = grow - m * HIDDEN;
        const float* Um = (m == 0 ? Uz : (m == 1 ? Ur : Uh));
        const float2* u2 = (const float2*)(Um + ri * HIDDEN + half * 50);
        #pragma unroll
        for (int k = 0; k < 25; ++k) ureg[k] = u2[k];
    } else {
        const int ts = t - 600;                // 0..423
        const int lim = ((L < MAXC) ? L : MAXC) * 3 * HIDDEN;
        for (int k = ts; k < lim; k += 424) {
            int dd = k / 300, rr = k - dd * 300;
            const float* s = a4 + dd * 1200 + rr;
            a_lds[k] = (s[0] + s[300]) + (s[600] + s[900]);
        }
    }
    if (t < 112) { h0[t] = 0.f; h1[t] = 0.f; }
    __syncthreads();

    // ---- first step (d = L-1, node 0): parent h = 0 -> pure pointwise ----
    {
        const int dl = L - 1;
        if (t < HIDDEN) {
            float az, ah;
            if (dl < MAXC) {
                az = a_lds[dl * 300 + t];
                ah = a_lds[dl * 300 + 2 * HIDDEN + t];
            } else {
                const float* s = a4 + dl * 1200;
                az = (s[t] + s[300 + t]) + (s[600 + t] + s[900 + t]);
                const float* s2 = s + 2 * HIDDEN;
                ah = (s2[t] + s2[300 + t]) + (s2[600 + t] + s2[900 + t]);
            }
            float z = fminf(fmaxf(az, 0.f), 1.f);          // Hardtanh(0,1)
            h1[t] = z * tanhf(ah);                         // (1-z)*0 + z*tanh(a_h)
        }
    }
    __syncthreads();

    float* hc = h1;
    float* hn = h0;
    for (int d = L - 2; d >= 0; --d) {
        if (t < 400) {                         // z and r rows (0..199)
            float adv;
            if (half == 0) {
                if (d < MAXC) adv = a_lds[d * 300 + grow];
                else {
                    const float* s = a4 + d * 1200 + grow;
                    adv = (s[0] + s[300]) + (s[600] + s[900]);
                }
            } else adv = 0.f;
            const float2* h2 = (const float2*)(hc + half * 50);   // 2-addr broadcast
            float a0 = 0.f, a1 = 0.f;
            #pragma unroll
            for (int k = 0; k < 25; ++k) {
                float2 u = ureg[k], x = h2[k];
                a0 += u.x * x.x; a1 += u.y * x.y;
            }
            float p = a0 + a1;
            p += __shfl_xor(p, 1);
            if (half == 0) {
                float v = fminf(fmaxf(adv + p, 0.f), 1.f);        // Hardtanh(0,1)
                if (grow < HIDDEN) zbuf[grow] = v;                           // z
                else               rbuf[grow - HIDDEN] = v * hc[grow - HIDDEN]; // r*h
            }
        }
        __syncthreads();
        if (t >= 400 && t < 600) {             // c rows (200..299) + state update
            float adv;
            if (half == 0) {
                if (d < MAXC) adv = a_lds[d * 300 + grow];
                else {
                    const float* s = a4 + d * 1200 + grow;
                    adv = (s[0] + s[300]) + (s[600] + s[900]);
                }
            } else adv = 0.f;
            const float2* r2 = (const float2*)(rbuf + half * 50);
            float a0 = 0.f, a1 = 0.f;
            #pragma unroll
            for (int k = 0; k < 25; ++k) {
                float2 u = ureg[k], x = r2[k];
                a0 += u.x * x.x; a1 += u.y * x.y;
            }
            float p = a0 + a1;
            p += __shfl_xor(p, 1);
            if (half == 0) {
                int i = grow - 200;
                float c = tanhf(adv + p);
                float z = zbuf[i];
                hn[i] = (1.f - z) * hc[i] + z * c;
            }
        }
        __syncthreads();
        float* tmp = hc; hc = hn; hn = tmp;
    }

    if (t < NCLASS) {
        float acc = bout[t];
        const float* wr = Wout + t * HIDDEN;
        for (int j = 0; j < HIDDEN; ++j) acc += wr[j] * hc[j];
        ov[t] = acc;
    }
    __syncthreads();
    if (t == 0) {
        float mx = fmaxf(fmaxf(ov[0], ov[1]), fmaxf(ov[2], ov[3]));
        float e0 = expf(ov[0] - mx), e1 = expf(ov[1] - mx);
        float e2 = expf(ov[2] - mx), e3 = expf(ov[3] - mx);
        float s = e0 + e1 + e2 + e3;
        out[0] = e0 / s; out[1] = e1 / s; out[2] = e2 / s; out[3] = e3 / s;
    }
}

extern "C" void kernel_launch(void* const* d_in, const int* in_sizes, int n_in,
                              void* d_out, int out_size, void* d_ws, size_t ws_size,
                              hipStream_t stream) {
    const float* xvals = (const float*)d_in[0];
    const int*   xidx  = (const int*)d_in[1];
    const int*   tree  = (const int*)d_in[2];
    const int*   npar  = (const int*)d_in[3];
    const float* E     = (const float*)d_in[4];
    const float* Wz    = (const float*)d_in[5];
    const float* Uz    = (const float*)d_in[6];
    const float* bz    = (const float*)d_in[7];
    const float* Wr    = (const float*)d_in[8];
    const float* Ur    = (const float*)d_in[9];
    const float* br    = (const float*)d_in[10];
    const float* Wh    = (const float*)d_in[11];
    const float* Uh    = (const float*)d_in[12];
    const float* bh    = (const float*)d_in[13];
    const float* Wout  = (const float*)d_in[14];
    const float* bout  = (const float*)d_in[15];

    int*   len = (int*)d_ws;
    float* a4  = (float*)((char*)d_ws + 64);

    k_prep<<<PREP_BLKS, NTHR_P, 0, stream>>>(xvals, xidx, tree, npar, E,
                                             Wz, bz, Wr, br, Wh, bh, len, a4);
    k_gru<<<1, NTHR_G, 0, stream>>>(Uz, Ur, Uh, Wout, bout, len, a4, (float*)d_out);
}